// Round 9
// baseline (373.079 us; speedup 1.0000x reference)
//
#include <hip/hip_runtime.h>
#include <stdint.h>

typedef uint32_t u32;
typedef unsigned long long u64;

#define LB_TILE 4096   // 16 elems/thread
#define OW_TILE 4096   // 16 rounds of 256
#define RUN 32

// scal[] slots
#define S_MAXT 1
#define S_DSTAR 2
#define S_NEED 3
#define S_U 5

// ---------------- decoupled-lookback exclusive scan (1 dispatch) ----------------
__global__ void scan_lb(const u32* __restrict__ in, u32* __restrict__ out, int n,
                        u64* __restrict__ desc){
  __shared__ u32 sh[256];
  __shared__ u32 shPrefix;
  int tid=threadIdx.x, t=blockIdx.x;
  int base = t*LB_TILE + tid*16;
  u32 v[16]; u32 s=0;
#pragma unroll
  for(int k=0;k<16;k++){ u32 xv=(base+k<n)?in[base+k]:0u; v[k]=s; s+=xv; }
  sh[tid]=s; __syncthreads();
  for(int o=1;o<256;o<<=1){
    u32 y=(tid>=o)?sh[tid-o]:0u;
    __syncthreads();
    sh[tid]+=y;
    __syncthreads();
  }
  u32 tileEx = (tid==0)?0u:sh[tid-1];
  u32 agg = sh[255];
  if(tid==0){
    u32 prefix=0u;
    if(t==0){
      atomicExch(&desc[0], ((u64)agg<<32)|2ull);
    } else {
      atomicExch(&desc[t], ((u64)agg<<32)|1ull);
      int j=t-1;
      while(true){
        u64 d=atomicAdd(&desc[j],0ull);
        u32 st=(u32)d;
        if(st==0u) continue;
        prefix += (u32)(d>>32);
        if(st==2u) break;
        --j;
      }
      atomicExch(&desc[t], ((u64)(prefix+agg)<<32)|2ull);
    }
    shPrefix=prefix;
  }
  __syncthreads();
  u32 p=shPrefix+tileEx;
#pragma unroll
  for(int k=0;k<16;k++){ if(base+k<n) out[base+k]=p+v[k]; }
}

// ---------------- onesweep radix pass, u32 keys (stable) ----------------
__global__ __launch_bounds__(256) void ow32(const u32* __restrict__ in,
    u32* __restrict__ outk, const u32* __restrict__ gbase, u64* __restrict__ desc,
    int shift, int n){
  __shared__ u32 hist[256], bd[256], cnt2[256];
  __shared__ u32 cnt4[4][256];
  int tid=threadIdx.x, b=blockIdx.x, w=tid>>6, lane=tid&63;
  int base=b*OW_TILE;
  hist[tid]=0u; cnt2[tid]=0u;
  cnt4[0][tid]=0u; cnt4[1][tid]=0u; cnt4[2][tid]=0u; cnt4[3][tid]=0u;
  __syncthreads();
  u32 k[16]; bool act[16];
#pragma unroll
  for(int i=0;i<16;i++){
    int p=base+i*256+tid; act[i]=(p<n);
    k[i]=act[i]?in[p]:0u;
    if(act[i]) atomicAdd(&hist[(k[i]>>shift)&255u],1u);
  }
  __syncthreads();
  u32 agg=hist[tid];
  if(b==0){
    atomicExch(&desc[tid], ((u64)agg<<32)|2ull);
    bd[tid]=gbase[tid];
  } else {
    atomicExch(&desc[(size_t)b*256+tid], ((u64)agg<<32)|1ull);
    u32 pre=0u; int j=b-1;
    while(true){
      u64 d=atomicAdd(&desc[(size_t)j*256+tid],0ull);
      u32 st=(u32)d;
      if(st==0u) continue;
      pre+=(u32)(d>>32);
      if(st==2u) break;
      --j;
    }
    atomicExch(&desc[(size_t)b*256+tid], ((u64)(pre+agg)<<32)|2ull);
    bd[tid]=gbase[tid]+pre;
  }
  __syncthreads();
#pragma unroll
  for(int i=0;i<16;i++){
    u32 dig=(k[i]>>shift)&255u;
    u64 m=__ballot(act[i]?1:0);
    for(int bb=0;bb<8;bb++){
      u64 bl=__ballot((int)((dig>>bb)&1u));
      m &= ((dig>>bb)&1u)?bl:~bl;
    }
    u32 rb=(u32)__popcll(m&((1ull<<lane)-1ull));
    if(act[i]&&rb==0u) cnt4[w][dig]=(u32)__popcll(m);
    __syncthreads();
    if(act[i]){
      u32 off=cnt2[dig]+rb;
      for(int w2=0;w2<w;w2++) off+=cnt4[w2][dig];
      u32 pos=bd[dig]+off;
      if(pos<(u32)n) outk[pos]=k[i];   // guard: no-op when digit math is exact
    }
    __syncthreads();
    cnt2[tid]+=cnt4[0][tid]+cnt4[1][tid]+cnt4[2][tid]+cnt4[3][tid];
    cnt4[0][tid]=0u; cnt4[1][tid]=0u; cnt4[2][tid]=0u; cnt4[3][tid]=0u;
    __syncthreads();
  }
}

// ---------------- onesweep radix pass, u64 keys (stable) ----------------
__global__ __launch_bounds__(256) void ow64(const u64* __restrict__ in,
    u64* __restrict__ outk, const u32* __restrict__ gbase, u64* __restrict__ desc,
    int shift, const u32* __restrict__ dCount, int cap){
  __shared__ u32 hist[256], bd[256], cnt2[256];
  __shared__ u32 cnt4[4][256];
  int n=(int)((*dCount)<(u32)cap?(*dCount):(u32)cap);
  int tid=threadIdx.x, b=blockIdx.x, w=tid>>6, lane=tid&63;
  int base=b*OW_TILE;
  hist[tid]=0u; cnt2[tid]=0u;
  cnt4[0][tid]=0u; cnt4[1][tid]=0u; cnt4[2][tid]=0u; cnt4[3][tid]=0u;
  __syncthreads();
  u64 k[16]; bool act[16];
#pragma unroll
  for(int i=0;i<16;i++){
    int p=base+i*256+tid; act[i]=(p<n);
    k[i]=act[i]?in[p]:0ull;
    if(act[i]) atomicAdd(&hist[(u32)(k[i]>>shift)&255u],1u);
  }
  __syncthreads();
  u32 agg=hist[tid];
  if(b==0){
    atomicExch(&desc[tid], ((u64)agg<<32)|2ull);
    bd[tid]=gbase[tid];
  } else {
    atomicExch(&desc[(size_t)b*256+tid], ((u64)agg<<32)|1ull);
    u32 pre=0u; int j=b-1;
    while(true){
      u64 d=atomicAdd(&desc[(size_t)j*256+tid],0ull);
      u32 st=(u32)d;
      if(st==0u) continue;
      pre+=(u32)(d>>32);
      if(st==2u) break;
      --j;
    }
    atomicExch(&desc[(size_t)b*256+tid], ((u64)(pre+agg)<<32)|2ull);
    bd[tid]=gbase[tid]+pre;
  }
  __syncthreads();
#pragma unroll
  for(int i=0;i<16;i++){
    u32 dig=(u32)(k[i]>>shift)&255u;
    u64 m=__ballot(act[i]?1:0);
    for(int bb=0;bb<8;bb++){
      u64 bl=__ballot((int)((dig>>bb)&1u));
      m &= ((dig>>bb)&1u)?bl:~bl;
    }
    u32 rb=(u32)__popcll(m&((1ull<<lane)-1ull));
    if(act[i]&&rb==0u) cnt4[w][dig]=(u32)__popcll(m);
    __syncthreads();
    if(act[i]){
      u32 off=cnt2[dig]+rb;
      for(int w2=0;w2<w;w2++) off+=cnt4[w2][dig];
      u32 pos=bd[dig]+off;
      if(pos<(u32)n) outk[pos]=k[i];
    }
    __syncthreads();
    cnt2[tid]+=cnt4[0][tid]+cnt4[1][tid]+cnt4[2][tid]+cnt4[3][tid];
    cnt4[0][tid]=0u; cnt4[1][tid]=0u; cnt4[2][tid]=0u; cnt4[3][tid]=0u;
    __syncthreads();
  }
}

// ---------------- pipeline kernels ----------------
// edge hists + packed u32 key (src<<16|tgt): every 8-bit digit window is clean
__global__ void k_edge0(const u32* __restrict__ src, const u32* __restrict__ tgt,
                        u32* cntS, u32* cntT, u32* keyA, int E){
  int j=blockIdx.x*256+threadIdx.x;
  if(j>=E) return;
  u32 s=src[j], t=tgt[j];
  atomicAdd(&cntS[s],1u); atomicAdd(&cntT[t],1u);
  keyA[j]=(s<<16)|t;
}

__global__ void k_deg2m(const u32* __restrict__ src, const u32* __restrict__ tgt,
                        const u32* __restrict__ cntS, const u32* __restrict__ cntT,
                        u32* deg, int* scal, int E){
  __shared__ int mx;
  if(threadIdx.x==0) mx=-1;
  __syncthreads();
  int e=blockIdx.x*256+threadIdx.x;
  int loc=-1;
  if(e<E){
    u32 s=src[e], t=tgt[e];
    u32 w0=cntS[t], w2=cntT[s];
    if(w0){ atomicAdd(&deg[s],w0); loc=(int)(s>t?s:t); }
    if(w2){ atomicAdd(&deg[t],w2); if((int)t>loc) loc=(int)t; }
  }
  if(loc>=0) atomicMax(&mx,loc);
  __syncthreads();
  if(threadIdx.x==0 && mx>=0) atomicMax(&scal[S_MAXT],mx);
}

__global__ void k_degNodeHist(const u32* __restrict__ cntS, const u32* __restrict__ cntT,
                              u32* deg, u32* dh, int NN, const int* __restrict__ scal){
  int v=blockIdx.x*256+threadIdx.x;
  if(v>=NN) return;
  u32 d=deg[v]+cntS[v]*cntT[v];
  deg[v]=d;
  if(v<=scal[S_MAXT]){ if(d>65535u)d=65535u; atomicAdd(&dh[d],1u); }
}

__global__ void k_dstar1b(const u32* __restrict__ dh, int* scal){
  __shared__ u32 part[256];
  __shared__ u32 sc[256];
  int t=threadIdx.x;
  long long kk=(((long long)scal[S_MAXT])+1)>>1;
  u32 s=0;
  for(int i=0;i<256;i++) s+=dh[t*256+i];
  part[t]=s; sc[t]=s; __syncthreads();
  for(int o=1;o<256;o<<=1){
    u32 y=(t>=o)?sc[t-o]:0u; __syncthreads();
    sc[t]+=y; __syncthreads();
  }
  if(kk==0){ if(t==0){ scal[S_DSTAR]=-1; scal[S_NEED]=0; } return; }
  long long cum=(long long)(sc[t]-part[t]);
  if(kk-1>=cum && kk-1<cum+(long long)part[t]){
    long long c=cum;
    for(int i=0;i<256;i++){
      u32 h=dh[t*256+i];
      if(kk-1>=c && kk-1<c+(long long)h){ scal[S_DSTAR]=t*256+i; scal[S_NEED]=(int)(kk-c); break; }
      c+=h;
    }
  }
}

__global__ void k_ef(const u32* __restrict__ deg, u32* ef, int NN, const int* __restrict__ scal){
  int v=blockIdx.x*256+threadIdx.x;
  if(v>NN) return;
  ef[v] = (v<NN && v<=scal[S_MAXT] && (int)deg[v]==scal[S_DSTAR]) ? 1u:0u;
}

__global__ void k_keep(const u32* __restrict__ deg, const u32* __restrict__ rankEq,
                       u32* keep, int NN, const int* __restrict__ scal){
  int v=blockIdx.x*256+threadIdx.x;
  if(v>=NN) return;
  int d=(int)deg[v]; int ds=scal[S_DSTAR]; int need=scal[S_NEED];
  u32 kp=1u;
  if(d<ds) kp=0u;
  else if(d==ds && (int)rankEq[v]<need) kp=0u;
  keep[v]=kp;
}

__global__ void k_keptCnt(const u32* __restrict__ src, const u32* __restrict__ tgt,
                          const u32* __restrict__ keep, u32* kc, int E){
  int j=blockIdx.x*256+threadIdx.x;
  if(j<E && keep[src[j]]) atomicAdd(&kc[tgt[j]],1u);
}

// fold cntS/cntT into the 4 edge-sort digit bases (block p: 0=S&255,1=S>>8,2=T&255,3=T>>8)
__global__ void k_gbase4(const u32* __restrict__ cntS, const u32* __restrict__ cntT,
                         u32* __restrict__ gbase, int NN){
  __shared__ u32 sh[256];
  int p=blockIdx.x, d=threadIdx.x;
  const u32* c=(p<2)?cntS:cntT;
  u32 s=0;
  if((p&1)==0){ for(int i=d;i<NN;i+=256) s+=c[i]; }
  else { int s0=d*256, s1=s0+256; if(s1>NN)s1=NN; for(int i=s0;i<s1;i++) s+=c[i]; }
  sh[d]=s; __syncthreads();
  for(int o=1;o<256;o<<=1){
    u32 y=(d>=o)?sh[d-o]:0u; __syncthreads();
    sh[d]+=y; __syncthreads();
  }
  gbase[p*256+d]=sh[d]-s;
}

// exclusive scan of H 256-bin histograms, one block
__global__ void k_scan256(const u32* __restrict__ hg, u32* __restrict__ gb, int H){
  __shared__ u32 sh[256];
  int t=threadIdx.x;
  for(int hh=0;hh<H;hh++){
    u32 v=hg[hh*256+t];
    sh[t]=v; __syncthreads();
    for(int o=1;o<256;o<<=1){
      u32 y=(t>=o)?sh[t-o]:0u; __syncthreads();
      sh[t]+=y; __syncthreads();
    }
    gb[hh*256+t]=sh[t]-v;
    __syncthreads();
  }
}

__global__ void k_cntk(const u32* __restrict__ C, const u32* __restrict__ keep,
                       const u32* __restrict__ keptCnt, u32* cntk, int E){
  int e=blockIdx.x*256+threadIdx.x;
  if(e>E) return;
  if(e==E){ cntk[e]=0u; return; }
  u32 ke=C[e];
  u32 s=ke>>16, te=ke&0xFFFFu;
  cntk[e]=(keep[s]&keep[te])?keptCnt[s]:0u;
}

// generate ONLY kept triplets, pre-compacted, in (e,i) order; key hs<<30|s<<15|te.
// fused: LDS digit histograms of the generated keys (for the triplet sort).
__global__ void k_gen_trik(const u32* __restrict__ C, const u32* __restrict__ H,
    const u32* __restrict__ rp, const u32* __restrict__ keep,
    const u32* __restrict__ startk, u64* __restrict__ trig, u32* __restrict__ histGT,
    int E, int cap){
  __shared__ u32 h0[256], h1[256];
  int tid=threadIdx.x;
  h0[tid]=0u; h1[tid]=0u;
  __syncthreads();
  int e=blockIdx.x*256+tid;
  if(e<E){
    u32 c0=startk[e], c1=startk[e+1];
    if(c0<c1){
      u32 ke=C[e];
      u32 s=ke>>16, te=ke&0xFFFFu;
      u32 r0=rp[0];
      u32 lb=rp[s]-r0, ub=rp[s+1]-r0;
      u32 idx=c0;
      for(u32 i=lb;i<ub&&idx<c1;++i){
        u32 hsv=H[i]>>16;
        if(keep[hsv]){
          if(idx<(u32)cap){
            u64 key=((u64)hsv<<30)|((u64)s<<15)|(u64)te;
            trig[idx]=key;
            atomicAdd(&h0[(u32)(key>>30)&255u],1u);
            atomicAdd(&h1[(u32)(key>>38)&255u],1u);
          }
          ++idx;
        }
      }
    }
  }
  __syncthreads();
  if(h0[tid]) atomicAdd(&histGT[tid],h0[tid]);
  if(h1[tid]) atomicAdd(&histGT[256+tid],h1[tid]);
}

__global__ void k_heads_present(const u64* __restrict__ tri, u32* __restrict__ hf,
    u32* __restrict__ present, const u32* __restrict__ dCount, int KC){
  int Tk=(int)((*dCount)<(u32)KC?(*dCount):(u32)KC);
  int q=blockIdx.x*256+threadIdx.x;
  if(q>KC) return;
  u32 f=0u;
  if(q<Tk){
    u64 key=tri[q];
    f=(q==0||(key>>30)!=(tri[q-1]>>30))?1u:0u;
    present[key>>30]=1u;
    present[(key>>15)&0x7FFFu]=1u;
    present[key&0x7FFFu]=1u;
  }
  hf[q]=f;
}

// fused: group starts (gs) + edge-index output; newid[v]=hsAll[KC+1+v]-U
__global__ void k_gs_ei(const u64* __restrict__ tri, const u32* __restrict__ hf,
    const u32* __restrict__ hsAll, u32* __restrict__ gs, float* __restrict__ out,
    int* scal, const u32* __restrict__ dCount, int KC, int out_size){
  int Tk=(int)((*dCount)<(u32)KC?(*dCount):(u32)KC);
  u32 U=hsAll[KC+1];
  int q=blockIdx.x*256+threadIdx.x;
  if(q==0){ scal[S_U]=(int)U; gs[U]=(u32)Tk; }
  if(q>=Tk) return;
  if(hf[q]) gs[hsAll[q+1]-1u]=(u32)q;
  u64 key=tri[q];
  int bs=(int)U*64;
  int i0=bs+q, i1=bs+Tk+q, i2=bs+2*Tk+q;
  if(i0<out_size) out[i0]=(float)(hsAll[(size_t)KC+1+(size_t)(key>>30)]-U);
  if(i1<out_size) out[i1]=(float)(hsAll[(size_t)KC+1+(size_t)((key>>15)&0x7FFFu)]-U);
  if(i2<out_size) out[i2]=(float)(hsAll[(size_t)KC+1+(size_t)(key&0x7FFFu)]-U);
}

// phase A: balanced 32-triplet runs; flush row-sums via atomicAdd on group change
__global__ __launch_bounds__(256) void k_xsum(const float* __restrict__ x,
    const u64* __restrict__ tri, const u32* __restrict__ hs,
    float* __restrict__ S1, float* __restrict__ S2,
    const u32* __restrict__ dCount, int KC){
  int Tk=(int)((*dCount)<(u32)KC?(*dCount):(u32)KC);
  int w=threadIdx.x>>6, lane=threadIdx.x&63;
  int r=blockIdx.x*4+w;
  int q0=r*RUN; if(q0>=Tk) return;
  int q1=q0+RUN; if(q1>Tk)q1=Tk;
  int gcur=(int)hs[q0+1]-1;
  float a1=0.f,a2=0.f;
  for(int q=q0;q<q1;q++){
    int g=(int)hs[q+1]-1;
    if(g!=gcur){
      atomicAdd(&S1[(size_t)gcur*64+lane],a1);
      atomicAdd(&S2[(size_t)gcur*64+lane],a2);
      a1=0.f;a2=0.f;gcur=g;
    }
    u64 key=tri[q];
    a1+=x[(size_t)((key>>15)&0x7FFFull)*64+lane];
    a2+=x[(size_t)(key&0x7FFFull)*64+lane];
  }
  atomicAdd(&S1[(size_t)gcur*64+lane],a1);
  atomicAdd(&S2[(size_t)gcur*64+lane],a2);
}

// phase B: per-group matvec, W in LDS (stride-65, conflict-free)
__global__ __launch_bounds__(256) void k_xmat(const float* __restrict__ x,
    const float* __restrict__ W, const float* __restrict__ b,
    const u64* __restrict__ tri, const u32* __restrict__ gs,
    const float* __restrict__ S1, const float* __restrict__ S2,
    float* __restrict__ out, const int* __restrict__ scal){
  __shared__ float Wl[192*65];
  __shared__ float sv[4][192];
  int tid=threadIdx.x;
  for(int j=tid;j<12288;j+=256){
    int r=j%192, o=j/192;      // j=(o*64+i)*3+k ; r=i*3+k
    Wl[r*65+o]=W[j];
  }
  __syncthreads();
  int U=scal[S_U];
  int w=tid>>6, lane=tid&63;
  float bv=b[lane];
  for(int g=blockIdx.x*4+w; g<U; g+=gridDim.x*4){
    u32 q0=gs[g], q1=gs[g+1];
    u32 uniq=(u32)(tri[q0]>>30);
    sv[w][lane]=x[(size_t)uniq*64+lane];
    sv[w][64+lane]=S1[(size_t)g*64+lane];
    sv[w][128+lane]=S2[(size_t)g*64+lane];
    float acc0=0.f, acc12=0.f;
#pragma unroll 4
    for(int ii=0;ii<64;ii++){
      acc0  += Wl[(ii*3+0)*65+lane]*sv[w][ii];
      acc12 += Wl[(ii*3+1)*65+lane]*sv[w][64+ii]
             + Wl[(ii*3+2)*65+lane]*sv[w][128+ii];
    }
    out[(size_t)g*64+lane] = bv + acc0 + acc12/(float)(q1-q0);
  }
}

extern "C" void kernel_launch(void* const* d_in, const int* in_sizes, int n_in,
                              void* d_out, int out_size, void* d_ws, size_t ws_size,
                              hipStream_t stream){
  const float* x = (const float*)d_in[0];
  const int*   ei = (const int*)d_in[1];
  const float* W = (const float*)d_in[2];
  const float* b = (const float*)d_in[3];
  int NN = in_sizes[0]/64;
  int E  = in_sizes[1]/2;
  const u32* src=(const u32*)ei;
  const u32* tgt=(const u32*)(ei+E);

  int KC = ((out_size/3 + OW_TILE-1)/OW_TILE)*OW_TILE; if(KC<OW_TILE) KC=OW_TILE;
  int B_E=(E+OW_TILE-1)/OW_TILE;
  int B_T=KC/OW_TILE;

  char* base=(char*)d_ws; size_t off=0;
  auto alloc=[&](size_t nInts)->u32*{
    u32* p=(u32*)(base+off);
    off += ( (nInts*4 + 255) & ~(size_t)255 );
    return p;
  };
  // ---- zero-zone (one memset) ----
  int* scal=(int*)alloc(64);
  u32* cntS=alloc(NN);
  u32* deg=alloc(NN); u32* degHist=alloc(65536);
  u32* keptCnt=alloc(NN);
  u32* histGT=alloc(2*256);
  u32* catA=alloc(2*(size_t)(NN+1));      // [ef | cntT]
  u64* descS=(u64*)alloc(2*1024);
  u64* descE=(u64*)alloc(2*(size_t)(4*B_E*256));
  u64* descT=(u64*)alloc(2*(size_t)(2*B_T*256));
  u32* hfp=alloc((size_t)KC+1+NN+1);      // [hf | present]
  float* S1=(float*)alloc((size_t)NN*64);
  float* S2=(float*)alloc((size_t)NN*64);
  size_t zoneBytes = off;
  // ---- rest (fully written before read) ----
  u32* ebA=alloc(E); u32* ebB=alloc(E); u32* ebC=alloc(E);
  u64* triA=(u64*)alloc(2*(size_t)KC); u64* triB=(u64*)alloc(2*(size_t)KC);
  u32* cntk=alloc(E+1); u32* startk=alloc(E+1);
  u32* catB=alloc(2*(size_t)(NN+1));      // scan of catA: [rankEq | rp']
  u32* gbaseE=alloc(4*256); u32* gbaseT=alloc(2*256);
  u32* keep=alloc(NN);
  u32* gs=alloc(NN+2);
  u32* hsAll=alloc((size_t)KC+1+NN+1);
  if(off > ws_size) return;

  u32* ef=catA; u32* cntT=catA+(NN+1);
  u32* rankEq=catB; u32* rp=catB+(NN+1);
  u32* hf=hfp; u32* present=hfp+(KC+1);
  const u32* dCount=startk+E;

  size_t descUsed=0;
  auto scan_ex=[&](const u32* in, u32* out, int n){
    int nb=(n+LB_TILE-1)/LB_TILE;
    scan_lb<<<nb,256,0,stream>>>(in,out,n,descS+descUsed);
    descUsed += (size_t)nb;
  };

  int gE=(E+255)/256, gE1=(E+256)/256;
  int gNN=(NN+255)/256, gNN1=(NN+256)/256;
  int gKC=(KC+255)/256, gKC1=(KC+256)/256;

  hipMemsetAsync(base,0,zoneBytes,stream);

  // edge hists + packed u32 key src<<16|tgt
  k_edge0<<<gE,256,0,stream>>>(src,tgt,cntS,cntT,ebA,E);
  // degree closed form + maxT
  k_deg2m<<<gE,256,0,stream>>>(src,tgt,cntS,cntT,deg,scal,E);
  k_degNodeHist<<<gNN,256,0,stream>>>(cntS,cntT,deg,degHist,NN,scal);
  // selection
  k_dstar1b<<<1,256,0,stream>>>(degHist,scal);
  k_ef<<<gNN1,256,0,stream>>>(deg,ef,NN,scal);
  scan_ex(catA,catB,2*(NN+1));            // [rankEq | rp'] in one scan
  k_keep<<<gNN,256,0,stream>>>(deg,rankEq,keep,NN,scal);
  k_keptCnt<<<gE,256,0,stream>>>(src,tgt,keep,keptCnt,E);

  // edge-sort digit bases folded from cntS/cntT (no data pre-read)
  k_gbase4<<<4,256,0,stream>>>(cntS,cntT,gbaseE,NN);
  // sort1 by src (shifts 16,24) then sort2 by tgt (shifts 0,8); C=ebC, H=ebB
  ow32<<<B_E,256,0,stream>>>(ebA,ebB,gbaseE+0*256,descE+(size_t)0*B_E*256,16,E);
  ow32<<<B_E,256,0,stream>>>(ebB,ebC,gbaseE+1*256,descE+(size_t)1*B_E*256,24,E);
  ow32<<<B_E,256,0,stream>>>(ebC,ebA,gbaseE+2*256,descE+(size_t)2*B_E*256,0,E);
  ow32<<<B_E,256,0,stream>>>(ebA,ebB,gbaseE+3*256,descE+(size_t)3*B_E*256,8,E);

  // kept counts / offsets, generate pre-compacted triplets (+ fused digit hists)
  k_cntk<<<gE1,256,0,stream>>>(ebC,keep,keptCnt,cntk,E);
  scan_ex(cntk,startk,E+1);
  k_gen_trik<<<gE,256,0,stream>>>(ebC,ebB,rp,keep,startk,triA,histGT,E,KC);

  // triplet sort by hs (2 onesweep passes, shifts 30/38 — zero-padded, clean)
  k_scan256<<<1,256,0,stream>>>(histGT,gbaseT,2);
  ow64<<<B_T,256,0,stream>>>(triA,triB,gbaseT+0*256,descT+(size_t)0*B_T*256,30,dCount,KC);
  ow64<<<B_T,256,0,stream>>>(triB,triA,gbaseT+1*256,descT+(size_t)1*B_T*256,38,dCount,KC);

  // groups + presence (concatenated single scan)
  k_heads_present<<<gKC1,256,0,stream>>>(triA,hf,present,dCount,KC);
  scan_ex(hfp,hsAll,KC+1+NN+1);
  float* outF=(float*)d_out;
  k_gs_ei<<<gKC,256,0,stream>>>(triA,hf,hsAll,gs,outF,scal,dCount,KC,out_size);

  // features: balanced scatter-sum then per-group matvec
  k_xsum<<<KC/(4*RUN),256,0,stream>>>(x,triA,hsAll,S1,S2,dCount,KC);
  k_xmat<<<768,256,0,stream>>>(x,W,b,triA,gs,S1,S2,outF,scal);
}

// Round 11
// 345.725 us; speedup vs baseline: 1.0791x; 1.0791x over previous
//
#include <hip/hip_runtime.h>
#include <stdint.h>

typedef uint32_t u32;
typedef unsigned long long u64;

#define LB_TILE 4096   // scan: 16 elems/thread

// scal[] slots
#define S_MAXT 1
#define S_DSTAR 2
#define S_NEED 3
#define S_U 5
#define S_EK 6

// ---------------- decoupled-lookback exclusive scan (1 dispatch) ----------------
__global__ void scan_lb(const u32* __restrict__ in, u32* __restrict__ out, int n,
                        u64* __restrict__ desc){
  __shared__ u32 sh[256];
  __shared__ u32 shPrefix;
  int tid=threadIdx.x, t=blockIdx.x;
  int base = t*LB_TILE + tid*16;
  u32 v[16]; u32 s=0;
#pragma unroll
  for(int k=0;k<16;k++){ u32 xv=(base+k<n)?in[base+k]:0u; v[k]=s; s+=xv; }
  sh[tid]=s; __syncthreads();
  for(int o=1;o<256;o<<=1){
    u32 y=(tid>=o)?sh[tid-o]:0u;
    __syncthreads();
    sh[tid]+=y;
    __syncthreads();
  }
  u32 tileEx = (tid==0)?0u:sh[tid-1];
  u32 agg = sh[255];
  if(tid==0){
    u32 prefix=0u;
    if(t==0){
      atomicExch(&desc[0], ((u64)agg<<32)|2ull);
    } else {
      atomicExch(&desc[t], ((u64)agg<<32)|1ull);
      int j=t-1;
      while(true){
        u64 d=atomicAdd(&desc[j],0ull);
        u32 st=(u32)d;
        if(st==0u) continue;
        prefix += (u32)(d>>32);
        if(st==2u) break;
        --j;
      }
      atomicExch(&desc[t], ((u64)(prefix+agg)<<32)|2ull);
    }
    shPrefix=prefix;
  }
  __syncthreads();
  u32 p=shPrefix+tileEx;
#pragma unroll
  for(int k=0;k<16;k++){ if(base+k<n) out[base+k]=p+v[k]; }
}

// ---------------- onesweep radix pass, u32 keys (stable), ROUNDS*256 tile ----------------
template<int ROUNDS>
__global__ __launch_bounds__(256) void ow32k(const u32* __restrict__ in,
    u32* __restrict__ outk, const u32* __restrict__ gbase, u64* __restrict__ desc,
    int shift, int hostN, const u32* __restrict__ devN, int cap){
  __shared__ u32 hist[256], bd[256], cnt2[256];
  __shared__ u32 cnt4[4][256];
  int n = (hostN>=0)?hostN:(int)((*devN)<(u32)cap?(*devN):(u32)cap);
  int tid=threadIdx.x, b=blockIdx.x, w=tid>>6, lane=tid&63;
  int base=b*ROUNDS*256;
  hist[tid]=0u; cnt2[tid]=0u;
  cnt4[0][tid]=0u; cnt4[1][tid]=0u; cnt4[2][tid]=0u; cnt4[3][tid]=0u;
  __syncthreads();
  u32 k[ROUNDS]; bool act[ROUNDS];
#pragma unroll
  for(int i=0;i<ROUNDS;i++){
    int p=base+i*256+tid; act[i]=(p<n);
    k[i]=act[i]?in[p]:0u;
    if(act[i]) atomicAdd(&hist[(k[i]>>shift)&255u],1u);
  }
  __syncthreads();
  u32 agg=hist[tid];
  if(b==0){
    atomicExch(&desc[tid], ((u64)agg<<32)|2ull);
    bd[tid]=gbase[tid];
  } else {
    atomicExch(&desc[(size_t)b*256+tid], ((u64)agg<<32)|1ull);
    u32 pre=0u; int j=b-1;
    while(true){
      u64 d=atomicAdd(&desc[(size_t)j*256+tid],0ull);
      u32 st=(u32)d;
      if(st==0u) continue;
      pre+=(u32)(d>>32);
      if(st==2u) break;
      --j;
    }
    atomicExch(&desc[(size_t)b*256+tid], ((u64)(pre+agg)<<32)|2ull);
    bd[tid]=gbase[tid]+pre;
  }
  __syncthreads();
#pragma unroll
  for(int i=0;i<ROUNDS;i++){
    u32 dig=(k[i]>>shift)&255u;
    u64 m=__ballot(act[i]?1:0);
    for(int bb=0;bb<8;bb++){
      u64 bl=__ballot((int)((dig>>bb)&1u));
      m &= ((dig>>bb)&1u)?bl:~bl;
    }
    u32 rb=(u32)__popcll(m&((1ull<<lane)-1ull));
    if(act[i]&&rb==0u) cnt4[w][dig]=(u32)__popcll(m);
    __syncthreads();
    if(act[i]){
      u32 off=cnt2[dig]+rb;
      for(int w2=0;w2<w;w2++) off+=cnt4[w2][dig];
      u32 pos=bd[dig]+off;
      if(pos<(u32)n) outk[pos]=k[i];
    }
    __syncthreads();
    cnt2[tid]+=cnt4[0][tid]+cnt4[1][tid]+cnt4[2][tid]+cnt4[3][tid];
    cnt4[0][tid]=0u; cnt4[1][tid]=0u; cnt4[2][tid]=0u; cnt4[3][tid]=0u;
    __syncthreads();
  }
}

// ---------------- onesweep radix pass, u64 keys (stable) ----------------
template<int ROUNDS>
__global__ __launch_bounds__(256) void ow64k(const u64* __restrict__ in,
    u64* __restrict__ outk, const u32* __restrict__ gbase, u64* __restrict__ desc,
    int shift, const u32* __restrict__ devN, int cap){
  __shared__ u32 hist[256], bd[256], cnt2[256];
  __shared__ u32 cnt4[4][256];
  int n=(int)((*devN)<(u32)cap?(*devN):(u32)cap);
  int tid=threadIdx.x, b=blockIdx.x, w=tid>>6, lane=tid&63;
  int base=b*ROUNDS*256;
  hist[tid]=0u; cnt2[tid]=0u;
  cnt4[0][tid]=0u; cnt4[1][tid]=0u; cnt4[2][tid]=0u; cnt4[3][tid]=0u;
  __syncthreads();
  u64 k[ROUNDS]; bool act[ROUNDS];
#pragma unroll
  for(int i=0;i<ROUNDS;i++){
    int p=base+i*256+tid; act[i]=(p<n);
    k[i]=act[i]?in[p]:0ull;
    if(act[i]) atomicAdd(&hist[(u32)(k[i]>>shift)&255u],1u);
  }
  __syncthreads();
  u32 agg=hist[tid];
  if(b==0){
    atomicExch(&desc[tid], ((u64)agg<<32)|2ull);
    bd[tid]=gbase[tid];
  } else {
    atomicExch(&desc[(size_t)b*256+tid], ((u64)agg<<32)|1ull);
    u32 pre=0u; int j=b-1;
    while(true){
      u64 d=atomicAdd(&desc[(size_t)j*256+tid],0ull);
      u32 st=(u32)d;
      if(st==0u) continue;
      pre+=(u32)(d>>32);
      if(st==2u) break;
      --j;
    }
    atomicExch(&desc[(size_t)b*256+tid], ((u64)(pre+agg)<<32)|2ull);
    bd[tid]=gbase[tid]+pre;
  }
  __syncthreads();
#pragma unroll
  for(int i=0;i<ROUNDS;i++){
    u32 dig=(u32)(k[i]>>shift)&255u;
    u64 m=__ballot(act[i]?1:0);
    for(int bb=0;bb<8;bb++){
      u64 bl=__ballot((int)((dig>>bb)&1u));
      m &= ((dig>>bb)&1u)?bl:~bl;
    }
    u32 rb=(u32)__popcll(m&((1ull<<lane)-1ull));
    if(act[i]&&rb==0u) cnt4[w][dig]=(u32)__popcll(m);
    __syncthreads();
    if(act[i]){
      u32 off=cnt2[dig]+rb;
      for(int w2=0;w2<w;w2++) off+=cnt4[w2][dig];
      u32 pos=bd[dig]+off;
      if(pos<(u32)n) outk[pos]=k[i];
    }
    __syncthreads();
    cnt2[tid]+=cnt4[0][tid]+cnt4[1][tid]+cnt4[2][tid]+cnt4[3][tid];
    cnt4[0][tid]=0u; cnt4[1][tid]=0u; cnt4[2][tid]=0u; cnt4[3][tid]=0u;
    __syncthreads();
  }
}

// ---------------- pipeline kernels ----------------
// edge hists + packed u32 key (src<<16|tgt): every 8-bit digit window is clean
__global__ void k_edge0(const u32* __restrict__ src, const u32* __restrict__ tgt,
                        u32* cntS, u32* cntT, u32* keyA, int E){
  int j=blockIdx.x*256+threadIdx.x;
  if(j>=E) return;
  u32 s=src[j], t=tgt[j];
  atomicAdd(&cntS[s],1u); atomicAdd(&cntT[t],1u);
  keyA[j]=(s<<16)|t;
}

__global__ void k_deg2m(const u32* __restrict__ src, const u32* __restrict__ tgt,
                        const u32* __restrict__ cntS, const u32* __restrict__ cntT,
                        u32* deg, int* scal, int E){
  __shared__ int mx;
  if(threadIdx.x==0) mx=-1;
  __syncthreads();
  int e=blockIdx.x*256+threadIdx.x;
  int loc=-1;
  if(e<E){
    u32 s=src[e], t=tgt[e];
    u32 w0=cntS[t], w2=cntT[s];
    if(w0){ atomicAdd(&deg[s],w0); loc=(int)(s>t?s:t); }
    if(w2){ atomicAdd(&deg[t],w2); if((int)t>loc) loc=(int)t; }
  }
  if(loc>=0) atomicMax(&mx,loc);
  __syncthreads();
  if(threadIdx.x==0 && mx>=0) atomicMax(&scal[S_MAXT],mx);
}

__global__ void k_degNodeHist(const u32* __restrict__ cntS, const u32* __restrict__ cntT,
                              u32* deg, u32* dh, int NN, const int* __restrict__ scal){
  int v=blockIdx.x*256+threadIdx.x;
  if(v>=NN) return;
  u32 d=deg[v]+cntS[v]*cntT[v];
  deg[v]=d;
  if(v<=scal[S_MAXT]){ if(d>65535u)d=65535u; atomicAdd(&dh[d],1u); }
}

__global__ void k_dstar1b(const u32* __restrict__ dh, int* scal){
  __shared__ u32 part[256];
  __shared__ u32 sc[256];
  int t=threadIdx.x;
  long long kk=(((long long)scal[S_MAXT])+1)>>1;
  u32 s=0;
  for(int i=0;i<256;i++) s+=dh[t*256+i];
  part[t]=s; sc[t]=s; __syncthreads();
  for(int o=1;o<256;o<<=1){
    u32 y=(t>=o)?sc[t-o]:0u; __syncthreads();
    sc[t]+=y; __syncthreads();
  }
  if(kk==0){ if(t==0){ scal[S_DSTAR]=-1; scal[S_NEED]=0; } return; }
  long long cum=(long long)(sc[t]-part[t]);
  if(kk-1>=cum && kk-1<cum+(long long)part[t]){
    long long c=cum;
    for(int i=0;i<256;i++){
      u32 h=dh[t*256+i];
      if(kk-1>=c && kk-1<c+(long long)h){ scal[S_DSTAR]=t*256+i; scal[S_NEED]=(int)(kk-c); break; }
      c+=h;
    }
  }
}

__global__ void k_ef(const u32* __restrict__ deg, u32* ef, int NN, const int* __restrict__ scal){
  int v=blockIdx.x*256+threadIdx.x;
  if(v>NN) return;
  ef[v] = (v<NN && v<=scal[S_MAXT] && (int)deg[v]==scal[S_DSTAR]) ? 1u:0u;
}

// keep flags + fill segment 2 of the node-scan input (keep*cntS)
__global__ void k_keep(const u32* __restrict__ deg, const u32* __restrict__ rankEq,
                       const u32* __restrict__ cntS, u32* keep, u32* kcsSeg,
                       int NN, const int* __restrict__ scal){
  int v=blockIdx.x*256+threadIdx.x;
  if(v>=NN) return;
  int d=(int)deg[v]; int ds=scal[S_DSTAR]; int need=scal[S_NEED];
  u32 kp=1u;
  if(d<ds) kp=0u;
  else if(d==ds && (int)rankEq[v]<need) kp=0u;
  keep[v]=kp;
  kcsSeg[v]=kp*cntS[v];
}

__global__ void k_keptCnt(const u32* __restrict__ src, const u32* __restrict__ tgt,
                          const u32* __restrict__ keep, u32* kc, int E){
  int j=blockIdx.x*256+threadIdx.x;
  if(j<E && keep[src[j]]) atomicAdd(&kc[tgt[j]],1u);
}

// digit bases: p=0,1 from cntS (src digits lo/hi); p=2,3 from keptCnt (tgt digits of kept hits).
// block 3 thread 255 publishes Ek = sum(keptCnt).
__global__ void k_gbase4(const u32* __restrict__ cntS, const u32* __restrict__ keptCnt,
                         u32* __restrict__ gbase, int NN, int* scal){
  __shared__ u32 sh[256];
  int p=blockIdx.x, d=threadIdx.x;
  const u32* c=(p<2)?cntS:keptCnt;
  u32 s=0;
  if((p&1)==0){ for(int i=d;i<NN;i+=256) s+=c[i]; }
  else { int s0=d*256, s1=s0+256; if(s1>NN)s1=NN; for(int i=s0;i<s1;i++) s+=c[i]; }
  sh[d]=s; __syncthreads();
  for(int o=1;o<256;o<<=1){
    u32 y=(d>=o)?sh[d-o]:0u; __syncthreads();
    sh[d]+=y; __syncthreads();
  }
  gbase[p*256+d]=sh[d]-s;
  if(p==3 && d==255) scal[S_EK]=(int)sh[255];
}

// exclusive scan of H 256-bin histograms, one block
__global__ void k_scan256(const u32* __restrict__ hg, u32* __restrict__ gb, int H){
  __shared__ u32 sh[256];
  int t=threadIdx.x;
  for(int hh=0;hh<H;hh++){
    u32 v=hg[hh*256+t];
    sh[t]=v; __syncthreads();
    for(int o=1;o<256;o<<=1){
      u32 y=(t>=o)?sh[t-o]:0u; __syncthreads();
      sh[t]+=y; __syncthreads();
    }
    gb[hh*256+t]=sh[t]-v;
    __syncthreads();
  }
}

// fused: cntk per rep edge + compact kept-src hits H2 (closed-form position, no scan)
// cat3out = scan of [cntS | keep*cntS | keptCnt]; rpS=cat3out, kcum=cat3out+NN1-E
__global__ void k_cntkCompact(const u32* __restrict__ C, const u32* __restrict__ keep,
    const u32* __restrict__ keptCnt, const u32* __restrict__ cat3out,
    u32* cntk, u32* __restrict__ H2, int E, int NN1){
  int e=blockIdx.x*256+threadIdx.x;
  if(e>E) return;
  if(e==E){ cntk[e]=0u; return; }
  u32 ke=C[e];
  u32 s=ke>>16, te=ke&0xFFFFu;
  u32 ks=keep[s];
  cntk[e]=(ks&keep[te])?keptCnt[s]:0u;
  if(ks){
    u32 rpS=cat3out[s];
    u32 kcum=cat3out[NN1+s]-(u32)E;     // segment-2 base = E
    H2[kcum+((u32)e-rpS)]=ke;
  }
}

// generate kept triplets, pre-compacted, in (e,i) order; key hs<<30|s<<15|te.
// H holds ONLY kept-src hits sorted by (tgt, src-order) -> no per-hit keep branch.
// fused: LDS digit histograms of generated keys (for the triplet sort).
__global__ void k_gen_trik(const u32* __restrict__ C, const u32* __restrict__ H,
    const u32* __restrict__ rpk, const u32* __restrict__ startk,
    u64* __restrict__ trig, u32* __restrict__ histGT, int E, int cap){
  __shared__ u32 h0[256], h1[256];
  int tid=threadIdx.x;
  h0[tid]=0u; h1[tid]=0u;
  __syncthreads();
  int e=blockIdx.x*256+tid;
  if(e<E){
    u32 c0=startk[e], c1=startk[e+1];
    if(c0<c1){
      u32 ke=C[e];
      u32 s=ke>>16, te=ke&0xFFFFu;
      u32 r0=rpk[0];
      u32 lb=rpk[s]-r0;
      u32 cnt=c1-c0;
      for(u32 o=0;o<cnt;++o){
        u32 idx=c0+o;
        if(idx<(u32)cap){
          u32 hsv=H[lb+o]>>16;
          u64 key=((u64)hsv<<30)|((u64)s<<15)|(u64)te;
          trig[idx]=key;
          atomicAdd(&h0[(u32)(key>>30)&255u],1u);
          atomicAdd(&h1[(u32)(key>>38)&255u],1u);
        }
      }
    }
  }
  __syncthreads();
  if(h0[tid]) atomicAdd(&histGT[tid],h0[tid]);
  if(h1[tid]) atomicAdd(&histGT[256+tid],h1[tid]);
}

__global__ void k_heads_present(const u64* __restrict__ tri, u32* __restrict__ hf,
    u32* __restrict__ present, const u32* __restrict__ dCount, int KC){
  int Tk=(int)((*dCount)<(u32)KC?(*dCount):(u32)KC);
  int q=blockIdx.x*256+threadIdx.x;
  if(q>KC) return;
  u32 f=0u;
  if(q<Tk){
    u64 key=tri[q];
    f=(q==0||(key>>30)!=(tri[q-1]>>30))?1u:0u;
    present[key>>30]=1u;
    present[(key>>15)&0x7FFFu]=1u;
    present[key&0x7FFFu]=1u;
  }
  hf[q]=f;
}

// fused: group starts (gs) + edge-index output; newid[v]=hsAll[KC+1+v]-U
__global__ void k_gs_ei(const u64* __restrict__ tri, const u32* __restrict__ hf,
    const u32* __restrict__ hsAll, u32* __restrict__ gs, float* __restrict__ out,
    int* scal, const u32* __restrict__ dCount, int KC, int out_size){
  int Tk=(int)((*dCount)<(u32)KC?(*dCount):(u32)KC);
  u32 U=hsAll[KC+1];
  int q=blockIdx.x*256+threadIdx.x;
  if(q==0){ scal[S_U]=(int)U; gs[U]=(u32)Tk; }
  if(q>=Tk) return;
  if(hf[q]) gs[hsAll[q+1]-1u]=(u32)q;
  u64 key=tri[q];
  int bs=(int)U*64;
  int i0=bs+q, i1=bs+Tk+q, i2=bs+2*Tk+q;
  if(i0<out_size) out[i0]=(float)(hsAll[(size_t)KC+1+(size_t)(key>>30)]-U);
  if(i1<out_size) out[i1]=(float)(hsAll[(size_t)KC+1+(size_t)((key>>15)&0x7FFFu)]-U);
  if(i2<out_size) out[i2]=(float)(hsAll[(size_t)KC+1+(size_t)(key&0x7FFFu)]-U);
}

#define RUN 32
// phase A: balanced 32-triplet runs; flush row-sums via atomicAdd on group change
__global__ __launch_bounds__(256) void k_xsum(const float* __restrict__ x,
    const u64* __restrict__ tri, const u32* __restrict__ hs,
    float* __restrict__ S1, float* __restrict__ S2,
    const u32* __restrict__ dCount, int KC){
  int Tk=(int)((*dCount)<(u32)KC?(*dCount):(u32)KC);
  int w=threadIdx.x>>6, lane=threadIdx.x&63;
  int r=blockIdx.x*4+w;
  int q0=r*RUN; if(q0>=Tk) return;
  int q1=q0+RUN; if(q1>Tk)q1=Tk;
  int gcur=(int)hs[q0+1]-1;
  float a1=0.f,a2=0.f;
  for(int q=q0;q<q1;q++){
    int g=(int)hs[q+1]-1;
    if(g!=gcur){
      atomicAdd(&S1[(size_t)gcur*64+lane],a1);
      atomicAdd(&S2[(size_t)gcur*64+lane],a2);
      a1=0.f;a2=0.f;gcur=g;
    }
    u64 key=tri[q];
    a1+=x[(size_t)((key>>15)&0x7FFFull)*64+lane];
    a2+=x[(size_t)(key&0x7FFFull)*64+lane];
  }
  atomicAdd(&S1[(size_t)gcur*64+lane],a1);
  atomicAdd(&S2[(size_t)gcur*64+lane],a2);
}

// phase B: per-group matvec, W in LDS (stride-65, conflict-free)
__global__ __launch_bounds__(256) void k_xmat(const float* __restrict__ x,
    const float* __restrict__ W, const float* __restrict__ b,
    const u64* __restrict__ tri, const u32* __restrict__ gs,
    const float* __restrict__ S1, const float* __restrict__ S2,
    float* __restrict__ out, const int* __restrict__ scal){
  __shared__ float Wl[192*65];
  __shared__ float sv[4][192];
  int tid=threadIdx.x;
  for(int j=tid;j<12288;j+=256){
    int r=j%192, o=j/192;      // j=(o*64+i)*3+k ; r=i*3+k
    Wl[r*65+o]=W[j];
  }
  __syncthreads();
  int U=scal[S_U];
  int w=tid>>6, lane=tid&63;
  float bv=b[lane];
  for(int g=blockIdx.x*4+w; g<U; g+=gridDim.x*4){
    u32 q0=gs[g], q1=gs[g+1];
    u32 uniq=(u32)(tri[q0]>>30);
    sv[w][lane]=x[(size_t)uniq*64+lane];
    sv[w][64+lane]=S1[(size_t)g*64+lane];
    sv[w][128+lane]=S2[(size_t)g*64+lane];
    float acc0=0.f, acc12=0.f;
#pragma unroll 4
    for(int ii=0;ii<64;ii++){
      acc0  += Wl[(ii*3+0)*65+lane]*sv[w][ii];
      acc12 += Wl[(ii*3+1)*65+lane]*sv[w][64+ii]
             + Wl[(ii*3+2)*65+lane]*sv[w][128+ii];
    }
    out[(size_t)g*64+lane] = bv + acc0 + acc12/(float)(q1-q0);
  }
}

extern "C" void kernel_launch(void* const* d_in, const int* in_sizes, int n_in,
                              void* d_out, int out_size, void* d_ws, size_t ws_size,
                              hipStream_t stream){
  const float* x = (const float*)d_in[0];
  const int*   ei = (const int*)d_in[1];
  const float* W = (const float*)d_in[2];
  const float* b = (const float*)d_in[3];
  int NN = in_sizes[0]/64;
  int E  = in_sizes[1]/2;
  int NN1 = NN+1;
  const u32* src=(const u32*)ei;
  const u32* tgt=(const u32*)(ei+E);

  const int TE=1024, TT=2048;                 // tile sizes (4 / 8 rounds)
  int KC = ((out_size/3 + TT-1)/TT)*TT; if(KC<TT) KC=TT;
  int B_E=(E+TE-1)/TE;
  int B_T=KC/TT;

  char* base=(char*)d_ws; size_t off=0;
  auto alloc=[&](size_t nInts)->u32*{
    u32* p=(u32*)(base+off);
    off += ( (nInts*4 + 255) & ~(size_t)255 );
    return p;
  };
  // ---- zero-zone (one memset) ----
  int* scal=(int*)alloc(64);
  u32* cat3=alloc(3*(size_t)NN1);         // [cntS | keep*cntS | keptCnt], pads stay 0
  u32* cntT=alloc(NN1);
  u32* deg=alloc(NN); u32* degHist=alloc(65536);
  u32* histGT=alloc(2*256);
  u64* descS=(u64*)alloc(2*1024);
  u64* descE=(u64*)alloc(2*(size_t)(4*B_E*256));
  u64* descT=(u64*)alloc(2*(size_t)(2*B_T*256));
  u32* hfp=alloc((size_t)KC+1+NN1);       // [hf | present]
  float* S1=(float*)alloc((size_t)NN*64);
  float* S2=(float*)alloc((size_t)NN*64);
  size_t zoneBytes = off;
  // ---- rest (fully written before read) ----
  u32* ebA=alloc(E); u32* ebB=alloc(E); u32* ebC=alloc(E);
  u64* triA=(u64*)alloc(2*(size_t)KC); u64* triB=(u64*)alloc(2*(size_t)KC);
  u32* cntk=alloc(E+1); u32* startk=alloc(E+1);
  u32* cat3out=alloc(3*(size_t)NN1);
  u32* gbaseE=alloc(4*256); u32* gbaseT=alloc(2*256);
  u32* ef=alloc(NN1); u32* rankEq=alloc(NN1);
  u32* keep=alloc(NN);
  u32* gs=alloc(NN+2);
  u32* hsAll=alloc((size_t)KC+1+NN1);
  if(off > ws_size) return;

  u32* cntS=cat3; u32* kcsSeg=cat3+NN1; u32* keptCnt=cat3+2*(size_t)NN1;
  u32* rpk=cat3out+2*(size_t)NN1;
  u32* hf=hfp; u32* present=hfp+(KC+1);
  const u32* dCount=startk+E;
  const u32* dEk=(const u32*)&scal[S_EK];

  size_t descUsed=0;
  auto scan_ex=[&](const u32* in, u32* out, int n){
    int nb=(n+LB_TILE-1)/LB_TILE;
    scan_lb<<<nb,256,0,stream>>>(in,out,n,descS+descUsed);
    descUsed += (size_t)nb;
  };

  int gE=(E+255)/256, gE1=(E+256)/256;
  int gNN=(NN+255)/256, gNN1=(NN+256)/256;
  int gKC=(KC+255)/256, gKC1=(KC+256)/256;

  hipMemsetAsync(base,0,zoneBytes,stream);

  // edge hists + packed u32 key src<<16|tgt
  k_edge0<<<gE,256,0,stream>>>(src,tgt,cntS,cntT,ebA,E);
  // degree closed form + maxT
  k_deg2m<<<gE,256,0,stream>>>(src,tgt,cntS,cntT,deg,scal,E);
  k_degNodeHist<<<gNN,256,0,stream>>>(cntS,cntT,deg,degHist,NN,scal);
  // selection
  k_dstar1b<<<1,256,0,stream>>>(degHist,scal);
  k_ef<<<gNN1,256,0,stream>>>(deg,ef,NN,scal);
  scan_ex(ef,rankEq,NN1);
  k_keep<<<gNN,256,0,stream>>>(deg,rankEq,cntS,keep,kcsSeg,NN,scal);
  k_keptCnt<<<gE,256,0,stream>>>(src,tgt,keep,keptCnt,E);

  // node-scan [cntS | keep*cntS | keptCnt] -> [rpS | kcum' | rpk']
  scan_ex(cat3,cat3out,3*NN1);
  // digit bases: src digits from cntS, tgt digits from keptCnt; publishes Ek
  k_gbase4<<<4,256,0,stream>>>(cntS,keptCnt,gbaseE,NN,scal);

  // src sort (full E): ebA -> ebB -> ebC  (C = ebC)
  ow32k<4><<<B_E,256,0,stream>>>(ebA,ebB,gbaseE+0*256,descE+(size_t)0*B_E*256,16,E,nullptr,0);
  ow32k<4><<<B_E,256,0,stream>>>(ebB,ebC,gbaseE+1*256,descE+(size_t)1*B_E*256,24,E,nullptr,0);

  // cntk + compact kept-src hits (H2 = ebA, closed-form positions)
  k_cntkCompact<<<gE1,256,0,stream>>>(ebC,keep,keptCnt,cat3out,cntk,ebA,E,NN1);
  scan_ex(cntk,startk,E+1);

  // tgt sort of kept hits (Ek elems): ebA -> ebB -> ebA  (H = ebA)
  ow32k<4><<<B_E,256,0,stream>>>(ebA,ebB,gbaseE+2*256,descE+(size_t)2*B_E*256,0,-1,dEk,E);
  ow32k<4><<<B_E,256,0,stream>>>(ebB,ebA,gbaseE+3*256,descE+(size_t)3*B_E*256,8,-1,dEk,E);

  // generate pre-compacted kept triplets (+ fused digit hists)
  k_gen_trik<<<gE,256,0,stream>>>(ebC,ebA,rpk,startk,triA,histGT,E,KC);

  // triplet sort by hs (2 onesweep passes, shifts 30/38)
  k_scan256<<<1,256,0,stream>>>(histGT,gbaseT,2);
  ow64k<8><<<B_T,256,0,stream>>>(triA,triB,gbaseT+0*256,descT+(size_t)0*B_T*256,30,dCount,KC);
  ow64k<8><<<B_T,256,0,stream>>>(triB,triA,gbaseT+1*256,descT+(size_t)1*B_T*256,38,dCount,KC);

  // groups + presence (concatenated single scan)
  k_heads_present<<<gKC1,256,0,stream>>>(triA,hf,present,dCount,KC);
  scan_ex(hfp,hsAll,KC+1+NN1);
  float* outF=(float*)d_out;
  k_gs_ei<<<gKC,256,0,stream>>>(triA,hf,hsAll,gs,outF,scal,dCount,KC,out_size);

  // features: balanced scatter-sum then per-group matvec
  k_xsum<<<KC/(4*RUN),256,0,stream>>>(x,triA,hsAll,S1,S2,dCount,KC);
  k_xmat<<<768,256,0,stream>>>(x,W,b,triA,gs,S1,S2,outF,scal);
}